// Round 5
// baseline (66.125 us; speedup 1.0000x reference)
//
#include <hip/hip_runtime.h>

#define NB 32
#define RR 128
#define FF 128
#define SB 132  // LDS row stride for transposed b: 132*4B = 528B, 16B-aligned rows,
                // 4-way write conflict (~1.58x) on staging, conflict-free b128 reads

// v6: 512 threads/block -> 2 waves/SIMD (was 1).
// v5 post-mortem: issue-early/write-late staging split was NEUTRAL (65.7 vs
// 65.4), and v1(8 barriers)==v3(1 barrier) earlier -> staging order, barrier
// count, and LDS traffic are all non-bottlenecks. Remaining mechanism: with
// 256 threads and 75.7 KB LDS we ran 4 waves/CU = 1 wave/SIMD -- every
// ds_read->FMA chain and every post-fill cold global load stalls with no
// other wave to hide it (only unroll-ILP). Fix: same 16-row tile, same grid
// (256 blocks, XCD-chunked swizzle), same single-stage staging + ONE barrier,
// but 512 threads: 1 row x 4 j per thread => 8 waves/block, 2 waves/SIMD,
// and per-thread staging halves (9 float4). b-reads: lanes 32-63 mirror
// lanes 0-31 (2 rows/wave share b) -> same-address LDS broadcast, free.
// Still no d_ws use: the 268 MB harness poison fill stays the only big HBM user.
__global__ __launch_bounds__(512) void gauss_fused(const float* __restrict__ x1,
                                                   const float* __restrict__ x2,
                                                   const float* __restrict__ sigma,
                                                   const float* __restrict__ mean,
                                                   float* __restrict__ out) {
  __shared__ __align__(16) float sh_b[FF * SB];   // 67584 B, transposed [f][j]
  __shared__ __align__(16) float sh_a[16 * FF];   // 8192 B, 16 x1 rows, mean folded

  // XCD-chunked mapping: dispatch d -> XCD d&7 (round-robin, 8 XCDs).
  // XCD x serves n = 4x .. 4x+3, 8 i-tiles each (grid 256 = 8 XCDs x 4 n x 8 tiles).
  const int d = blockIdx.x;
  const int xcd = d & 7;
  const int k = d >> 3;                  // 0..31 within-XCD slot
  const int n = (xcd << 2) + (k >> 3);   // 4 consecutive n per XCD
  const int i0 = (k & 7) << 4;           // 16 rows per block
  const int tid = threadIdx.x;
  const int tx = tid & 31;   // j-quad
  const int ty = tid >> 5;   // 0..15: one row per thread

  const float mval = mean[0];
  const float sg = sigma[0];
  const float cneg = -1.0f / (2.0f * sg * sg);

  const float* __restrict__ x2base = x2 + (size_t)n * RR * FF;

  // Staging split across 512 threads: low 8 bits give v4's (jj, fo) pattern
  // (8-lane groups read contiguous 128 B row segments, 4-way LDS write
  // conflict); bit 8 picks the f-half. 8 b float4 + 1 a float4 per thread.
  const int jj = (tid >> 3) & 31;        // j within each 32-row chunk
  const int fo = (tid & 7) << 2;         // f-quad within each 32-f chunk
  const int hb = (tid >> 8) << 6;        // f-half base: 0 or 64

  // ---- cluster ALL staging global loads first (9 float4 in flight) ----
#define LDQ(fc, p) \
  *(const float4*)(x2base + (size_t)(jj + ((p) << 5)) * FF + hb + ((fc) << 5) + fo)
  const float4 q00 = LDQ(0, 0), q01 = LDQ(0, 1), q02 = LDQ(0, 2), q03 = LDQ(0, 3);
  const float4 q10 = LDQ(1, 0), q11 = LDQ(1, 1), q12 = LDQ(1, 2), q13 = LDQ(1, 3);
#undef LDQ
  const float4 va = ((const float4*)(x1 + (size_t)(n * RR + i0) * FF))[tid];

  // ---- drain to LDS ----
  ((float4*)sh_a)[tid] = make_float4(va.x - mval, va.y - mval, va.z - mval, va.w - mval);
#define STW(q, fc, p)                                 \
  {                                                   \
    const int f0 = hb + ((fc) << 5) + fo;             \
    const int j = jj + ((p) << 5);                    \
    sh_b[(f0 + 0) * SB + j] = (q).x;                  \
    sh_b[(f0 + 1) * SB + j] = (q).y;                  \
    sh_b[(f0 + 2) * SB + j] = (q).z;                  \
    sh_b[(f0 + 3) * SB + j] = (q).w;                  \
  }
  STW(q00, 0, 0) STW(q01, 0, 1) STW(q02, 0, 2) STW(q03, 0, 3)
  STW(q10, 1, 0) STW(q11, 1, 1) STW(q12, 1, 2) STW(q13, 1, 3)
#undef STW
  __syncthreads();  // the ONLY barrier

  float acc0 = 0.f, acc1 = 0.f, acc2 = 0.f, acc3 = 0.f;
  const int j0 = tx << 2;
  const float* __restrict__ arow = sh_a + ty * FF;

#pragma unroll 4
  for (int fq = 0; fq < 32; ++fq) {
    const float4 a = *(const float4*)(arow + (fq << 2));  // broadcast b128 (1 addr/32 lanes)
#pragma unroll
    for (int c = 0; c < 4; ++c) {
      const float4 b = *(const float4*)(sh_b + ((fq << 2) + c) * SB + j0);  // lane-consecutive b128
      const float ac = (c == 0) ? a.x : (c == 1) ? a.y : (c == 2) ? a.z : a.w;
      float dd;
      dd = ac - b.x; acc0 = fmaf(dd, dd, acc0);
      dd = ac - b.y; acc1 = fmaf(dd, dd, acc1);
      dd = ac - b.z; acc2 = fmaf(dd, dd, acc2);
      dd = ac - b.w; acc3 = fmaf(dd, dd, acc3);
    }
  }

  // kernel_value = exp(-ds / (2 sigma^2)); softmax over j (row = 32 lanes x
  // 4 regs; xor offsets <=16 stay within each 32-lane row-group).
  const float k0 = __expf(acc0 * cneg);
  const float k1 = __expf(acc1 * cneg);
  const float k2 = __expf(acc2 * cneg);
  const float k3 = __expf(acc3 * cneg);

  float mx = fmaxf(fmaxf(k0, k1), fmaxf(k2, k3));
#pragma unroll
  for (int off = 16; off >= 1; off >>= 1) mx = fmaxf(mx, __shfl_xor(mx, off, 64));
  const float e0 = __expf(k0 - mx);
  const float e1 = __expf(k1 - mx);
  const float e2 = __expf(k2 - mx);
  const float e3 = __expf(k3 - mx);
  float ssum = e0 + e1 + e2 + e3;
#pragma unroll
  for (int off = 16; off >= 1; off >>= 1) ssum += __shfl_xor(ssum, off, 64);
  const float r = 1.0f / ssum;

  *(float4*)(out + (size_t)(n * RR + i0 + ty) * RR + j0) =
      make_float4(e0 * r, e1 * r, e2 * r, e3 * r);
}

extern "C" void kernel_launch(void* const* d_in, const int* in_sizes, int n_in,
                              void* d_out, int out_size, void* d_ws, size_t ws_size,
                              hipStream_t stream) {
  const float* x1 = (const float*)d_in[0];
  const float* x2 = (const float*)d_in[1];
  const float* sigma = (const float*)d_in[2];
  const float* mean = (const float*)d_in[3];
  float* out = (float*)d_out;
  (void)d_ws; (void)ws_size;  // deliberately unused: keep the 268 MB ws poison off our path

  gauss_fused<<<dim3(NB * 8), dim3(512), 0, stream>>>(x1, x2, sigma, mean, out);
}

// Round 6
// 65.783 us; speedup vs baseline: 1.0052x; 1.0052x over previous
//
#include <hip/hip_runtime.h>

#define NB 32
#define RR 128
#define FF 128
#define SB 132  // LDS row stride for transposed b: 132*4B = 528B, 16B-aligned rows,
                // 4-way write conflict (~1.58x) on staging, conflict-free b128 reads

// v7 == v4 (best measured, 65.4 us): whole-slice LDS staging, ONE barrier,
// XCD-chunked swizzle, clustered staging loads, 2 rows/thread.
// Session evidence: v1(69.4, 8-barrier pipeline) ~ v3(68.6, 1 barrier) ~
// v5(65.7, issue-early dbuf) ~ v6(66.1, 2 waves/SIMD) -- all throughput and
// latency-hiding knobs neutral; only the XCD L2-locality swizzle moved time
// (-3.2 us, v3->v4). Remaining 65.4 = harness fill 40.2 + fixed gap ~15 +
// ~10 us kernel floor (post-fill cold-HBM staging; L3 evicted each iter by
// the 268 MB poison fill). Kernel-source-side levers exhausted.
// Still no d_ws use: the poison fill stays the only big HBM user.
__global__ __launch_bounds__(256) void gauss_fused(const float* __restrict__ x1,
                                                   const float* __restrict__ x2,
                                                   const float* __restrict__ sigma,
                                                   const float* __restrict__ mean,
                                                   float* __restrict__ out) {
  __shared__ __align__(16) float sh_b[FF * SB];   // 67584 B, transposed [f][j]
  __shared__ __align__(16) float sh_a[16 * FF];   // 8192 B, 16 x1 rows, mean folded

  // XCD-chunked mapping: dispatch d -> XCD d&7 (round-robin, 8 XCDs).
  // XCD x serves n = 4x .. 4x+3, 8 i-tiles each (grid 256 = 8 XCDs x 4 n x 8 tiles).
  const int d = blockIdx.x;
  const int xcd = d & 7;
  const int k = d >> 3;                  // 0..31 within-XCD slot
  const int n = (xcd << 2) + (k >> 3);   // 4 consecutive n per XCD
  const int i0 = (k & 7) << 4;           // 16 rows per block
  const int tid = threadIdx.x;
  const int tx = tid & 31;   // j-quad
  const int ty = tid >> 5;   // 0..7 -> rows i0+ty and i0+ty+8

  const float mval = mean[0];
  const float sg = sigma[0];
  const float cneg = -1.0f / (2.0f * sg * sg);

  const float* __restrict__ x2base = x2 + (size_t)n * RR * FF;
  const int jj = tid >> 3;        // 0..31: j within each 32-row chunk
  const int fo = (tid & 7) << 2;  // 0,4,...,28: f-quad within each 32-f chunk

  // ---- staging: cluster ALL global loads first (18 float4 in flight) ----
  float4 q0, q1, q2, q3, q4, q5, q6, q7, q8, q9, q10, q11, q12, q13, q14, q15;
#define LDQ(fc, p) *(const float4*)(x2base + (size_t)(jj + ((p) << 5)) * FF + ((fc) << 5) + fo)
  q0 = LDQ(0, 0);  q1 = LDQ(0, 1);  q2 = LDQ(0, 2);  q3 = LDQ(0, 3);
  q4 = LDQ(1, 0);  q5 = LDQ(1, 1);  q6 = LDQ(1, 2);  q7 = LDQ(1, 3);
  q8 = LDQ(2, 0);  q9 = LDQ(2, 1);  q10 = LDQ(2, 2); q11 = LDQ(2, 3);
  q12 = LDQ(3, 0); q13 = LDQ(3, 1); q14 = LDQ(3, 2); q15 = LDQ(3, 3);
#undef LDQ
  const float4* asrc = (const float4*)(x1 + (size_t)(n * RR + i0) * FF);
  const float4 v0 = asrc[tid];
  const float4 v1 = asrc[tid + 256];

  // ---- drain to LDS ----
  ((float4*)sh_a)[tid] = make_float4(v0.x - mval, v0.y - mval, v0.z - mval, v0.w - mval);
  ((float4*)sh_a)[tid + 256] = make_float4(v1.x - mval, v1.y - mval, v1.z - mval, v1.w - mval);
#define STW(q, fc, p)                                    \
  {                                                      \
    const int f0 = ((fc) << 5) + fo;                     \
    const int j = jj + ((p) << 5);                       \
    sh_b[(f0 + 0) * SB + j] = (q).x;                     \
    sh_b[(f0 + 1) * SB + j] = (q).y;                     \
    sh_b[(f0 + 2) * SB + j] = (q).z;                     \
    sh_b[(f0 + 3) * SB + j] = (q).w;                     \
  }
  STW(q0, 0, 0)  STW(q1, 0, 1)  STW(q2, 0, 2)  STW(q3, 0, 3)
  STW(q4, 1, 0)  STW(q5, 1, 1)  STW(q6, 1, 2)  STW(q7, 1, 3)
  STW(q8, 2, 0)  STW(q9, 2, 1)  STW(q10, 2, 2) STW(q11, 2, 3)
  STW(q12, 3, 0) STW(q13, 3, 1) STW(q14, 3, 2) STW(q15, 3, 3)
#undef STW
  __syncthreads();  // the ONLY barrier

  float acc00 = 0.f, acc01 = 0.f, acc02 = 0.f, acc03 = 0.f;
  float acc10 = 0.f, acc11 = 0.f, acc12 = 0.f, acc13 = 0.f;
  const int j0 = tx << 2;
  const float* __restrict__ arow0 = sh_a + ty * FF;
  const float* __restrict__ arow1 = sh_a + (ty + 8) * FF;

#pragma unroll 4
  for (int fq = 0; fq < 32; ++fq) {
    const float4 a0 = *(const float4*)(arow0 + (fq << 2));  // broadcast b128
    const float4 a1 = *(const float4*)(arow1 + (fq << 2));
#pragma unroll
    for (int c = 0; c < 4; ++c) {
      const float4 b = *(const float4*)(sh_b + ((fq << 2) + c) * SB + j0);  // lane-consecutive b128
      const float a0c = (c == 0) ? a0.x : (c == 1) ? a0.y : (c == 2) ? a0.z : a0.w;
      const float a1c = (c == 0) ? a1.x : (c == 1) ? a1.y : (c == 2) ? a1.z : a1.w;
      float d;
      d = a0c - b.x; acc00 = fmaf(d, d, acc00);
      d = a0c - b.y; acc01 = fmaf(d, d, acc01);
      d = a0c - b.z; acc02 = fmaf(d, d, acc02);
      d = a0c - b.w; acc03 = fmaf(d, d, acc03);
      d = a1c - b.x; acc10 = fmaf(d, d, acc10);
      d = a1c - b.y; acc11 = fmaf(d, d, acc11);
      d = a1c - b.z; acc12 = fmaf(d, d, acc12);
      d = a1c - b.w; acc13 = fmaf(d, d, acc13);
    }
  }

  // kernel_value = exp(-ds / (2 sigma^2)); softmax over j for BOTH rows.
  // Row = 32 lanes x 4 regs; xor offsets <32 stay within each 32-lane half.
  const float k00 = __expf(acc00 * cneg);
  const float k01 = __expf(acc01 * cneg);
  const float k02 = __expf(acc02 * cneg);
  const float k03 = __expf(acc03 * cneg);
  const float k10 = __expf(acc10 * cneg);
  const float k11 = __expf(acc11 * cneg);
  const float k12 = __expf(acc12 * cneg);
  const float k13 = __expf(acc13 * cneg);

  float mx0 = fmaxf(fmaxf(k00, k01), fmaxf(k02, k03));
  float mx1 = fmaxf(fmaxf(k10, k11), fmaxf(k12, k13));
#pragma unroll
  for (int off = 16; off >= 1; off >>= 1) {
    mx0 = fmaxf(mx0, __shfl_xor(mx0, off, 64));
    mx1 = fmaxf(mx1, __shfl_xor(mx1, off, 64));
  }
  const float e00 = __expf(k00 - mx0);
  const float e01 = __expf(k01 - mx0);
  const float e02 = __expf(k02 - mx0);
  const float e03 = __expf(k03 - mx0);
  const float e10 = __expf(k10 - mx1);
  const float e11 = __expf(k11 - mx1);
  const float e12 = __expf(k12 - mx1);
  const float e13 = __expf(k13 - mx1);
  float s0 = e00 + e01 + e02 + e03;
  float s1 = e10 + e11 + e12 + e13;
#pragma unroll
  for (int off = 16; off >= 1; off >>= 1) {
    s0 += __shfl_xor(s0, off, 64);
    s1 += __shfl_xor(s1, off, 64);
  }
  const float r0 = 1.0f / s0;
  const float r1 = 1.0f / s1;

  *(float4*)(out + (size_t)(n * RR + i0 + ty) * RR + j0) =
      make_float4(e00 * r0, e01 * r0, e02 * r0, e03 * r0);
  *(float4*)(out + (size_t)(n * RR + i0 + ty + 8) * RR + j0) =
      make_float4(e10 * r1, e11 * r1, e12 * r1, e13 * r1);
}

extern "C" void kernel_launch(void* const* d_in, const int* in_sizes, int n_in,
                              void* d_out, int out_size, void* d_ws, size_t ws_size,
                              hipStream_t stream) {
  const float* x1 = (const float*)d_in[0];
  const float* x2 = (const float*)d_in[1];
  const float* sigma = (const float*)d_in[2];
  const float* mean = (const float*)d_in[3];
  float* out = (float*)d_out;
  (void)d_ws; (void)ws_size;  // deliberately unused: keep the 268 MB ws poison off our path

  gauss_fused<<<dim3(NB * 8), dim3(256), 0, stream>>>(x1, x2, sigma, mean, out);
}